// Round 6
// baseline (307.482 us; speedup 1.0000x reference)
//
#include <hip/hip_runtime.h>

// AttentionBlock: B=8, C=128, H=W=128, GROUPS=8, HEADS=8, HEAD_DIM=16
// R7: dispatch-count attack. Affine collapse as R6, but gram+reduce+fold fused
// into ONE ordinary kernel (grid 256 = #CUs, 1 block/CU -> all co-resident) with
// device-scope atomic-flag handoffs (magic ^ blk; harness re-poison clears stale
// flags each iteration). Phase B writes G directly as bf16 + f32 diag only.
// k_out unchanged. 2 kernels total (+1 harness fill).

#define NPOS 16384
#define MAGA 0xA11C0DE5u
#define MAGB 0xB22C0DE5u

typedef short short8 __attribute__((ext_vector_type(8)));   // 8 bf16
typedef float f32x4 __attribute__((ext_vector_type(4)));

__device__ __forceinline__ unsigned short f2bf(float f) {
    union { float f; unsigned u; } v; v.f = f;
    unsigned r = (v.u + 0x7fffu + ((v.u >> 16) & 1u)) >> 16;
    return (unsigned short)r;
}

// ---------------- K1: gram partial -> flag -> reduce slice -> flag -> fold ----
// grid 256 = 8 b x 32 slabs of 512 pos; 512 threads; LDS ~116.5 KB (1 block/CU).
__global__ __launch_bounds__(512, 1) void k_gramfold(
    const float* __restrict__ x,
    const float* __restrict__ gn_w, const float* __restrict__ gn_b,
    const float* __restrict__ w_in, const float* __restrict__ b_in,
    const float* __restrict__ w_out, const float* __restrict__ b_out,
    float* Gpart, float* mpart,
    unsigned int* flagA, unsigned int* flagB,
    unsigned short* Gbf, float* Gdiag,
    unsigned short* __restrict__ Mb, float* __restrict__ bias2) {

    __shared__ __align__(16) unsigned char SH[119296];
    // phase A: Xs bf16 [128][256] @0 (64KB); Tf f32 [128][132] @0 (67.6KB)
    // phase C: As @0, At @34816, Ts @69632 (each 34816 B)
    //          sW f32 @104448 (8KB); sm @112640 ss @113152 st @113664
    //          sv @114176 su @114688; red[8][128] @115200 (4KB)

    const int t = threadIdx.x;
    const int lane = t & 63, wv = t >> 6;
    const int q = lane >> 4, i16 = lane & 15;
    const int blk = blockIdx.x;
    const int b = blk >> 5, slab = blk & 31;
    const size_t d0 = (size_t)slab << 9;      // 512 pos per block

    // ================= Phase A: Gram partial (exact R6 k_gram) =================
    {
        unsigned short* Xs = (unsigned short*)SH;
        f32x4 acc[8];
        f32x4 macc = (f32x4){0.f, 0.f, 0.f, 0.f};
#pragma unroll
        for (int ct = 0; ct < 8; ++ct) acc[ct] = (f32x4){0.f, 0.f, 0.f, 0.f};
        const short8 ones = {(short)0x3F80, (short)0x3F80, (short)0x3F80, (short)0x3F80,
                             (short)0x3F80, (short)0x3F80, (short)0x3F80, (short)0x3F80};
        const float* xb = x + (size_t)b * (128 * NPOS) + d0;
        const int r0 = wv * 16 + i16;

        for (int cc = 0; cc < 2; ++cc) {
            if (cc) __syncthreads();
#pragma unroll
            for (int i = 0; i < 16; ++i) {
                int idx = t + i * 512;              // float4 index over [128][64]
                int c = idx >> 6, d4 = idx & 63;
                float4 v = *((const float4*)(xb + (size_t)c * NPOS + cc * 256) + d4);
                ushort4 o;
                o.x = f2bf(v.x); o.y = f2bf(v.y); o.z = f2bf(v.z); o.w = f2bf(v.w);
                int g = d4 >> 1;
                int sg = g ^ (c & 7);
                *(ushort4*)&Xs[c * 256 + (sg << 3) + ((d4 & 1) << 2)] = o;
            }
            __syncthreads();
#pragma unroll
            for (int ks = 0; ks < 8; ++ks) {
                int gd = ks * 4 + q;
                short8 af = *(const short8*)&Xs[r0 * 256 + ((gd ^ (r0 & 7)) << 3)];
                macc = __builtin_amdgcn_mfma_f32_16x16x32_bf16(af, ones, macc, 0, 0, 0);
#pragma unroll
                for (int ct = 0; ct < 8; ++ct) {
                    int rb = ct * 16 + i16;
                    short8 bb = *(const short8*)&Xs[rb * 256 + ((gd ^ (rb & 7)) << 3)];
                    acc[ct] = __builtin_amdgcn_mfma_f32_16x16x32_bf16(af, bb, acc[ct], 0, 0, 0);
                }
            }
        }
        if (i16 == 0) {
#pragma unroll
            for (int r = 0; r < 4; ++r)
                mpart[blk * 128 + wv * 16 + q * 4 + r] = macc[r];
        }
        __syncthreads();            // Xs dead -> reuse as f32 [128][132]

        float* Tf = (float*)SH;
#pragma unroll
        for (int ct = 0; ct < 8; ++ct)
#pragma unroll
            for (int r = 0; r < 4; ++r)
                Tf[(wv * 16 + q * 4 + r) * 132 + ct * 16 + i16] = acc[ct][r];
        __syncthreads();
        float4* gp = (float4*)(Gpart + (size_t)blk * 16384);
#pragma unroll
        for (int i = 0; i < 8; ++i) {
            int fi = t + i * 512;
            int row = fi >> 5, c4 = fi & 31;
            gp[row * 32 + c4] = *(float4*)&Tf[row * 132 + c4 * 4];
        }
    }
    __threadfence();
    __syncthreads();
    if (t == 0) atomicExch(&flagA[blk], MAGA ^ (unsigned)blk);

    // ================= Phase B: spin + reduce 1/32 slice =================
    if (t < 32) {
        unsigned exp = MAGA ^ (unsigned)(b * 32 + t);
        while (atomicAdd(&flagA[b * 32 + t], 0u) != exp) __builtin_amdgcn_s_sleep(2);
    }
    __syncthreads();
    __threadfence();

    float* sm = (float*)(SH + 112640);
    if (t < 128) {
        int off4 = slab * 128 + t;              // float4 index within batch G
        const float4* Gp4 = (const float4*)Gpart;
        float4 s = (float4){0.f, 0.f, 0.f, 0.f};
#pragma unroll 8
        for (int sl = 0; sl < 32; ++sl) {
            float4 v = Gp4[(size_t)(b * 32 + sl) * 4096 + off4];
            s.x += v.x; s.y += v.y; s.z += v.z; s.w += v.w;
        }
        int row = slab * 4 + (t >> 5);
        int col = (t & 31) * 4;
        ushort4 o;
        o.x = f2bf(s.x); o.y = f2bf(s.y); o.z = f2bf(s.z); o.w = f2bf(s.w);
        *(ushort4*)&Gbf[b * 16384 + row * 128 + col] = o;
        if ((t & 31) == slab)                   // this float4 holds diag (row,row)
            Gdiag[b * 128 + row] = ((float*)&s)[t >> 5];
    }
    if (slab == 0 && t < 128) {
        float ms = 0.f;
#pragma unroll 8
        for (int sl = 0; sl < 32; ++sl) ms += mpart[(b * 32 + sl) * 128 + t];
        sm[t] = ms;                             // fold runs in THIS block
    }
    __threadfence();
    __syncthreads();
    if (t == 0) atomicExch(&flagB[blk], MAGB ^ (unsigned)blk);

    if (slab != 0) return;

    // ================= Phase C (8 blocks): fold (exact R6 k_fold) =============
    if (t < 32) {
        unsigned exp = MAGB ^ (unsigned)(b * 32 + t);
        while (atomicAdd(&flagB[b * 32 + t], 0u) != exp) __builtin_amdgcn_s_sleep(2);
    }
    __syncthreads();
    __threadfence();

    unsigned short* As = (unsigned short*)SH;
    unsigned short* At = (unsigned short*)(SH + 34816);
    unsigned short* Ts = (unsigned short*)(SH + 69632);
    float* sW = (float*)(SH + 104448);
    float* ss = (float*)(SH + 113152);
    float* st = (float*)(SH + 113664);
    float* sv = (float*)(SH + 114176);
    float* su = (float*)(SH + 114688);
    float* red = (float*)(SH + 115200);         // [8][128]

    if (t < 128) {
        int g = t >> 4;
        float s1 = 0.f, s2 = 0.f;
#pragma unroll
        for (int k = 0; k < 16; ++k) {
            int c = g * 16 + k;
            s1 += sm[c];
            s2 += Gdiag[b * 128 + c];
        }
        const float invN = 1.0f / 262144.0f;
        float mean = s1 * invN;
        float var = s2 * invN - mean * mean;
        float rstd = rsqrtf(var + 1e-5f);
        float s = gn_w[t] * rstd;
        ss[t] = s;
        st[t] = gn_b[t] - mean * s;
    }
    __syncthreads();

    // A (+A^T) bf16 ; v,u partials
    {
        int c = t & 127, quarter = t >> 7;
        float v = 0.f, u = 0.f;
        const float* wr = w_in + c * 128 + quarter * 32;
        unsigned short* ar = &As[c * 136 + quarter * 32];
#pragma unroll
        for (int k = 0; k < 32; ++k) {
            int kg = quarter * 32 + k;
            float w = wr[k];
            float a = w * ss[kg];
            unsigned short ab = f2bf(a);
            ar[k] = ab;
            At[kg * 136 + c] = ab;
            v += w * st[kg];
            u += a * sm[kg];
        }
        red[quarter * 128 + c] = v;
        red[(4 + quarter) * 128 + c] = u;
    }
    // stage G (already bf16) -> Ts
    {
        const ushort4* gb4 = (const ushort4*)(Gbf + b * 16384);
#pragma unroll
        for (int i4 = t; i4 < 4096; i4 += 512) {
            int row = i4 >> 5, c4 = i4 & 31;
            *(ushort4*)&Ts[row * 136 + c4 * 4] = gb4[i4];
        }
    }
    __syncthreads();
    if (t < 128) {
        sv[t] = b_in[t] + red[t] + red[128 + t] + red[256 + t] + red[384 + t];
        su[t] = red[512 + t] + red[640 + t] + red[768 + t] + red[896 + t];
    }
    __syncthreads();

    // T = A @ G  (G symmetric)
    f32x4 tacc[8];
#pragma unroll
    for (int ct = 0; ct < 8; ++ct) tacc[ct] = (f32x4){0.f, 0.f, 0.f, 0.f};
    const int rA = wv * 16 + i16;
#pragma unroll
    for (int ks = 0; ks < 4; ++ks) {
        short8 af = *(const short8*)&As[rA * 136 + ks * 32 + q * 8];
#pragma unroll
        for (int ct = 0; ct < 8; ++ct) {
            short8 gbf = *(const short8*)&Ts[(ct * 16 + i16) * 136 + ks * 32 + q * 8];
            tacc[ct] = __builtin_amdgcn_mfma_f32_16x16x32_bf16(af, gbf, tacc[ct], 0, 0, 0);
        }
    }
    __syncthreads();
#pragma unroll
    for (int ct = 0; ct < 8; ++ct)
#pragma unroll
        for (int r = 0; r < 4; ++r)
            Ts[(wv * 16 + q * 4 + r) * 136 + ct * 16 + i16] = f2bf(tacc[ct][r]);
    __syncthreads();

    // S_h = T_h A_h^T + rank-1 ; softmax -> sW (wave = head)
    {
        f32x4 sacc = (f32x4){0.f, 0.f, 0.f, 0.f};
#pragma unroll
        for (int ks = 0; ks < 4; ++ks) {
            short8 tf = *(const short8*)&Ts[rA * 136 + ks * 32 + q * 8];
            short8 af = *(const short8*)&As[rA * 136 + ks * 32 + q * 8];
            sacc = __builtin_amdgcn_mfma_f32_16x16x32_bf16(tf, af, sacc, 0, 0, 0);
        }
        int J = wv * 16 + i16;
        float vJ = sv[J], uJ = su[J];
#pragma unroll
        for (int r = 0; r < 4; ++r) {
            int I = wv * 16 + q * 4 + r;
            float val = (sacc[r] + su[I] * vJ + sv[I] * uJ + 16384.f * sv[I] * vJ) * 0.25f;
            float mx = val;
#pragma unroll
            for (int msk = 1; msk < 16; msk <<= 1) mx = fmaxf(mx, __shfl_xor(mx, msk));
            float e = __expf(val - mx);
            float sum = e;
#pragma unroll
            for (int msk = 1; msk < 16; msk <<= 1) sum += __shfl_xor(sum, msk);
            sW[I * 16 + i16] = e / sum;
        }
    }
    __syncthreads();

    // P = w_out * blkdiag(W)  (VALU f32 -> bf16 into Ts) ; bias2 = P@sv + b_out
    {
        int c = t & 127, grp = t >> 7;
        unsigned short* Ps = Ts;
        float pb = 0.f;
#pragma unroll
        for (int hh = 0; hh < 2; ++hh) {
            int h = grp * 2 + hh;
            float wrow[16];
#pragma unroll
            for (int i = 0; i < 16; ++i) wrow[i] = w_out[c * 128 + h * 16 + i];
#pragma unroll
            for (int j = 0; j < 16; ++j) {
                float val = 0.f;
#pragma unroll
                for (int i = 0; i < 16; ++i) val += wrow[i] * sW[(h * 16 + i) * 16 + j];
                Ps[c * 136 + h * 16 + j] = f2bf(val);
                pb += val * sv[h * 16 + j];
            }
        }
        red[grp * 128 + c] = pb;
    }
    __syncthreads();
    if (t < 128)
        bias2[b * 128 + t] = b_out[t] + red[t] + red[128 + t] + red[256 + t] + red[384 + t];

    // M = P @ A  (MFMA: a = P rows, b = A^T rows)
    {
        f32x4 macc[8];
#pragma unroll
        for (int ct = 0; ct < 8; ++ct) macc[ct] = (f32x4){0.f, 0.f, 0.f, 0.f};
#pragma unroll
        for (int ks = 0; ks < 4; ++ks) {
            short8 pf = *(const short8*)&Ts[rA * 136 + ks * 32 + q * 8];
#pragma unroll
            for (int ct = 0; ct < 8; ++ct) {
                short8 atf = *(const short8*)&At[(ct * 16 + i16) * 136 + ks * 32 + q * 8];
                macc[ct] = __builtin_amdgcn_mfma_f32_16x16x32_bf16(pf, atf, macc[ct], 0, 0, 0);
            }
        }
        unsigned short* mb = Mb + (size_t)b * 16384;
#pragma unroll
        for (int ct = 0; ct < 8; ++ct)
#pragma unroll
            for (int r = 0; r < 4; ++r)
                mb[(wv * 16 + q * 4 + r) * 128 + ct * 16 + i16] = f2bf(macc[ct][r]);
    }
}

// ---------------- K2: out = x + M @ x + bias2 (unchanged) ----------------
__global__ __launch_bounds__(256, 4) void k_out(const float* __restrict__ x,
                                                const unsigned short* __restrict__ Mb,
                                                const float* __restrict__ bias2,
                                                float* __restrict__ out) {
    __shared__ unsigned short Xt[128 * 128];   // [p][k] bf16, granule-swizzled
    __shared__ float b2s[128];

    const int t = threadIdx.x;
    const int lane = t & 63, wv = t >> 6;
    const int q = lane >> 4, i16 = lane & 15;
    const int b = blockIdx.x >> 7;
    const int p0 = (blockIdx.x & 127) << 7;

    if (t < 128) b2s[t] = bias2[b * 128 + t];

    const float* xb = x + (size_t)b * (128 * NPOS) + p0;
#pragma unroll
    for (int i = 0; i < 16; ++i) {
        int p = ((i & 1) << 6) + lane;
        int kq = (wv << 3) + (i >> 1);
        const float* col = xb + (size_t)(kq * 4) * NPOS + p;
        float a0 = col[0];
        float a1 = col[NPOS];
        float a2 = col[2 * NPOS];
        float a3 = col[3 * NPOS];
        ushort4 o; o.x = f2bf(a0); o.y = f2bf(a1); o.z = f2bf(a2); o.w = f2bf(a3);
        int g = kq >> 1;
        int sg = g ^ (p & 7);
        *(ushort4*)&Xt[p * 128 + (sg << 3) + ((kq & 1) << 2)] = o;
    }
    __syncthreads();

    f32x4 acc[2][8];
#pragma unroll
    for (int a = 0; a < 2; ++a)
#pragma unroll
        for (int pt = 0; pt < 8; ++pt) acc[a][pt] = (f32x4){0.f, 0.f, 0.f, 0.f};

    const unsigned short* Mrow = Mb + (size_t)b * 16384;
#pragma unroll
    for (int ks = 0; ks < 4; ++ks) {
        short8 a0 = *(const short8*)&Mrow[(wv * 32 + i16) * 128 + ks * 32 + q * 8];
        short8 a1 = *(const short8*)&Mrow[(wv * 32 + 16 + i16) * 128 + ks * 32 + q * 8];
        int g = ks * 4 + q;
#pragma unroll
        for (int pt = 0; pt < 8; ++pt) {
            int pr = pt * 16 + i16;
            short8 bb = *(const short8*)&Xt[pr * 128 + ((g ^ (pr & 7)) << 3)];
            acc[0][pt] = __builtin_amdgcn_mfma_f32_16x16x32_bf16(a0, bb, acc[0][pt], 0, 0, 0);
            acc[1][pt] = __builtin_amdgcn_mfma_f32_16x16x32_bf16(a1, bb, acc[1][pt], 0, 0, 0);
        }
    }

    float* ob = out + (size_t)b * (128 * NPOS) + p0;
#pragma unroll
    for (int a = 0; a < 2; ++a) {
        int cb = wv * 32 + a * 16 + q * 4;
#pragma unroll
        for (int pt = 0; pt < 8; ++pt) {
            int p = pt * 16 + i16;
#pragma unroll
            for (int r = 0; r < 4; ++r) {
                int c = cb + r;
                ob[(size_t)c * NPOS + p] = acc[a][pt][r] + b2s[c] + xb[(size_t)c * NPOS + p];
            }
        }
    }
}

extern "C" void kernel_launch(void* const* d_in, const int* in_sizes, int n_in,
                              void* d_out, int out_size, void* d_ws, size_t ws_size,
                              hipStream_t stream) {
    const float* x    = (const float*)d_in[0];
    const float* gn_w = (const float*)d_in[1];
    const float* gn_b = (const float*)d_in[2];
    const float* w_in = (const float*)d_in[3];
    const float* b_in = (const float*)d_in[4];
    const float* w_out= (const float*)d_in[5];
    const float* b_out= (const float*)d_in[6];
    float* out = (float*)d_out;

    // workspace (bytes), total ~17.4 MB:
    char* ws = (char*)d_ws;
    float* Gpart          = (float*)(ws + 0);          // 256*16384*4 = 16777216
    float* mpart          = (float*)(ws + 16777216);   // 256*128*4   = 131072
    unsigned int* flagA   = (unsigned int*)(ws + 16908288);  // 1024
    unsigned int* flagB   = (unsigned int*)(ws + 16909312);  // 1024
    unsigned short* Gbf   = (unsigned short*)(ws + 16910336); // 8*16384*2 = 262144
    float* Gdiag          = (float*)(ws + 17172480);   // 4096
    float* bias2          = (float*)(ws + 17176576);   // 4096
    unsigned short* Mb    = (unsigned short*)(ws + 17180672); // 262144

    k_gramfold<<<dim3(256), dim3(512), 0, stream>>>(x, gn_w, gn_b, w_in, b_in,
                                                    w_out, b_out, Gpart, mpart,
                                                    flagA, flagB, Gbf, Gdiag,
                                                    Mb, bias2);
    k_out<<<dim3(1024), dim3(256), 0, stream>>>(x, Mb, bias2, out);
}

// Round 7
// 213.748 us; speedup vs baseline: 1.4385x; 1.4385x over previous
//
#include <hip/hip_runtime.h>

// AttentionBlock: B=8, C=128, H=W=128, GROUPS=8, HEADS=8, HEAD_DIM=16
// R8: affine collapse; gram+reduce+fold fused via LAST-ARRIVAL pattern (no
// spinning, scheduling-robust): 128 blocks compute Gram partials; per batch,
// the block that observes all 16 sibling flags set claims a winner slot and
// runs reduce(1MB)+fold in-block. Flags/claim use 64-bit magics (poison-proof);
// double-claim is idempotent. k_out unchanged. 2 kernels (+1 harness fill).

#define NPOS 16384
#define MAG64   0x9E3779B97F4A7C15ull
#define CLAIM64 0xC1A1317E9E3779B9ull

typedef short short8 __attribute__((ext_vector_type(8)));   // 8 bf16
typedef float f32x4 __attribute__((ext_vector_type(4)));

__device__ __forceinline__ unsigned short f2bf(float f) {
    union { float f; unsigned u; } v; v.f = f;
    unsigned r = (v.u + 0x7fffu + ((v.u >> 16) & 1u)) >> 16;
    return (unsigned short)r;
}

// ---------------- K1: gram partial -> last-arrival claim -> reduce+fold ------
// grid 128 = 8 b x 16 slabs of 1024 pos; 512 threads; LDS ~117 KB.
__global__ __launch_bounds__(512, 1) void k_gramfold(
    const float* __restrict__ x,
    const float* __restrict__ gn_w, const float* __restrict__ gn_b,
    const float* __restrict__ w_in, const float* __restrict__ b_in,
    const float* __restrict__ w_out, const float* __restrict__ b_out,
    float* Gpart, float* mpart,
    unsigned long long* flagS, unsigned long long* claim,
    unsigned short* __restrict__ Mb, float* __restrict__ bias2) {

    __shared__ __align__(16) unsigned char SH[119808];
    // phase A: Xs bf16 [128][256] @0 (64KB); Tf f32 [128][132] @0 (67.6KB)
    // tail:    As @0, At @34816, Ts @69632 (34816 each)
    //          sW @104448 (8KB); sm @112640; ss @113152; st @113664
    //          sv @114176; su @114688; Gdiag @115200; red[8][128] @115712
    __shared__ int winner_s;

    const int t = threadIdx.x;
    const int lane = t & 63, wv = t >> 6;
    const int q = lane >> 4, i16 = lane & 15;
    const int blk = blockIdx.x;
    const int b = blk >> 4, slab = blk & 15;
    const size_t d0 = (size_t)slab << 10;     // 1024 pos per block

    // ================= Phase A: Gram partial over 1024 pos =================
    {
        unsigned short* Xs = (unsigned short*)SH;
        f32x4 acc[8];
        f32x4 macc = (f32x4){0.f, 0.f, 0.f, 0.f};
#pragma unroll
        for (int ct = 0; ct < 8; ++ct) acc[ct] = (f32x4){0.f, 0.f, 0.f, 0.f};
        const short8 ones = {(short)0x3F80, (short)0x3F80, (short)0x3F80, (short)0x3F80,
                             (short)0x3F80, (short)0x3F80, (short)0x3F80, (short)0x3F80};
        const float* xb = x + (size_t)b * (128 * NPOS) + d0;
        const int r0 = wv * 16 + i16;

        for (int cc = 0; cc < 4; ++cc) {
            if (cc) __syncthreads();
#pragma unroll
            for (int i = 0; i < 16; ++i) {
                int idx = t + i * 512;              // float4 index over [128][64]
                int c = idx >> 6, d4 = idx & 63;
                float4 v = *((const float4*)(xb + (size_t)c * NPOS + cc * 256) + d4);
                ushort4 o;
                o.x = f2bf(v.x); o.y = f2bf(v.y); o.z = f2bf(v.z); o.w = f2bf(v.w);
                int g = d4 >> 1;
                int sg = g ^ (c & 7);
                *(ushort4*)&Xs[c * 256 + (sg << 3) + ((d4 & 1) << 2)] = o;
            }
            __syncthreads();
#pragma unroll
            for (int ks = 0; ks < 8; ++ks) {
                int gd = ks * 4 + q;
                short8 af = *(const short8*)&Xs[r0 * 256 + ((gd ^ (r0 & 7)) << 3)];
                macc = __builtin_amdgcn_mfma_f32_16x16x32_bf16(af, ones, macc, 0, 0, 0);
#pragma unroll
                for (int ct = 0; ct < 8; ++ct) {
                    int rb = ct * 16 + i16;
                    short8 bb = *(const short8*)&Xs[rb * 256 + ((gd ^ (rb & 7)) << 3)];
                    acc[ct] = __builtin_amdgcn_mfma_f32_16x16x32_bf16(af, bb, acc[ct], 0, 0, 0);
                }
            }
        }
        if (i16 == 0) {
#pragma unroll
            for (int r = 0; r < 4; ++r)
                mpart[blk * 128 + wv * 16 + q * 4 + r] = macc[r];
        }
        __syncthreads();            // Xs dead -> reuse as f32 [128][132]

        float* Tf = (float*)SH;
#pragma unroll
        for (int ct = 0; ct < 8; ++ct)
#pragma unroll
            for (int r = 0; r < 4; ++r)
                Tf[(wv * 16 + q * 4 + r) * 132 + ct * 16 + i16] = acc[ct][r];
        __syncthreads();
        float4* gp = (float4*)(Gpart + (size_t)blk * 16384);
#pragma unroll
        for (int i = 0; i < 8; ++i) {
            int fi = t + i * 512;
            int row = fi >> 5, c4 = fi & 31;
            gp[row * 32 + c4] = *(float4*)&Tf[row * 132 + c4 * 4];
        }
    }
    __threadfence();
    __syncthreads();

    // ======== publish flag, single check (no spin), claim if complete ========
    if (wv == 0) {
        if (lane == 0) atomicExch(&flagS[blk], MAG64 ^ (unsigned long long)blk);
        int pred = 1;
        if (lane < 16) {
            unsigned long long v = atomicAdd(&flagS[b * 16 + lane], 0ull);
            pred = (v == (MAG64 ^ (unsigned long long)(b * 16 + lane)));
        }
        int allok = __all(pred);
        if (lane == 0) {
            int win = 0;
            if (allok) {
                unsigned long long old = atomicExch(&claim[b], CLAIM64);
                win = (old != CLAIM64);
            }
            winner_s = win;
        }
    }
    __syncthreads();
    if (!winner_s) return;
    __threadfence();

    // ================= Tail (1 winner per batch): reduce + fold =============
    unsigned short* As = (unsigned short*)SH;
    unsigned short* At = (unsigned short*)(SH + 34816);
    unsigned short* Ts = (unsigned short*)(SH + 69632);
    float* sW    = (float*)(SH + 104448);
    float* sm    = (float*)(SH + 112640);
    float* ss    = (float*)(SH + 113152);
    float* st    = (float*)(SH + 113664);
    float* sv    = (float*)(SH + 114176);
    float* su    = (float*)(SH + 114688);
    float* Gdiag = (float*)(SH + 115200);
    float* red   = (float*)(SH + 115712);       // [8][128]

    // reduce 16 partials -> Ts (bf16) + Gdiag (f32); m -> sm
    {
        const float4* Gp4 = (const float4*)Gpart;
#pragma unroll
        for (int i = 0; i < 8; ++i) {
            int off4 = t + i * 512;              // float4 idx over G[128][128]
            int row = off4 >> 5, c4 = off4 & 31;
            float4 s = (float4){0.f, 0.f, 0.f, 0.f};
#pragma unroll
            for (int sl = 0; sl < 16; ++sl) {
                float4 v = Gp4[(size_t)(b * 16 + sl) * 4096 + off4];
                s.x += v.x; s.y += v.y; s.z += v.z; s.w += v.w;
            }
            ushort4 o;
            o.x = f2bf(s.x); o.y = f2bf(s.y); o.z = f2bf(s.z); o.w = f2bf(s.w);
            *(ushort4*)&Ts[row * 136 + c4 * 4] = o;
            if (c4 == (row >> 2)) Gdiag[row] = ((float*)&s)[row & 3];
        }
        if (t < 128) {
            float ms = 0.f;
#pragma unroll
            for (int sl = 0; sl < 16; ++sl) ms += mpart[(b * 16 + sl) * 128 + t];
            sm[t] = ms;
        }
    }
    __syncthreads();

    // stats
    if (t < 128) {
        int g = t >> 4;
        float s1 = 0.f, s2 = 0.f;
#pragma unroll
        for (int k = 0; k < 16; ++k) {
            int c = g * 16 + k;
            s1 += sm[c];
            s2 += Gdiag[c];
        }
        const float invN = 1.0f / 262144.0f;
        float mean = s1 * invN;
        float var = s2 * invN - mean * mean;
        float rstd = rsqrtf(var + 1e-5f);
        float s = gn_w[t] * rstd;
        ss[t] = s;
        st[t] = gn_b[t] - mean * s;
    }
    __syncthreads();

    // A (+A^T) bf16 ; v,u partials
    {
        int c = t & 127, quarter = t >> 7;
        float v = 0.f, u = 0.f;
        const float* wr = w_in + c * 128 + quarter * 32;
        unsigned short* ar = &As[c * 136 + quarter * 32];
#pragma unroll
        for (int k = 0; k < 32; ++k) {
            int kg = quarter * 32 + k;
            float w = wr[k];
            float a = w * ss[kg];
            unsigned short ab = f2bf(a);
            ar[k] = ab;
            At[kg * 136 + c] = ab;
            v += w * st[kg];
            u += a * sm[kg];
        }
        red[quarter * 128 + c] = v;
        red[(4 + quarter) * 128 + c] = u;
    }
    __syncthreads();
    if (t < 128) {
        sv[t] = b_in[t] + red[t] + red[128 + t] + red[256 + t] + red[384 + t];
        su[t] = red[512 + t] + red[640 + t] + red[768 + t] + red[896 + t];
    }
    __syncthreads();

    // T = A @ G  (G symmetric)
    f32x4 tacc[8];
#pragma unroll
    for (int ct = 0; ct < 8; ++ct) tacc[ct] = (f32x4){0.f, 0.f, 0.f, 0.f};
    const int rA = wv * 16 + i16;
#pragma unroll
    for (int ks = 0; ks < 4; ++ks) {
        short8 af = *(const short8*)&As[rA * 136 + ks * 32 + q * 8];
#pragma unroll
        for (int ct = 0; ct < 8; ++ct) {
            short8 gbf = *(const short8*)&Ts[(ct * 16 + i16) * 136 + ks * 32 + q * 8];
            tacc[ct] = __builtin_amdgcn_mfma_f32_16x16x32_bf16(af, gbf, tacc[ct], 0, 0, 0);
        }
    }
    __syncthreads();
#pragma unroll
    for (int ct = 0; ct < 8; ++ct)
#pragma unroll
        for (int r = 0; r < 4; ++r)
            Ts[(wv * 16 + q * 4 + r) * 136 + ct * 16 + i16] = f2bf(tacc[ct][r]);
    __syncthreads();

    // S_h = T_h A_h^T + rank-1 ; softmax -> sW (wave = head)
    {
        f32x4 sacc = (f32x4){0.f, 0.f, 0.f, 0.f};
#pragma unroll
        for (int ks = 0; ks < 4; ++ks) {
            short8 tf = *(const short8*)&Ts[rA * 136 + ks * 32 + q * 8];
            short8 af = *(const short8*)&As[rA * 136 + ks * 32 + q * 8];
            sacc = __builtin_amdgcn_mfma_f32_16x16x32_bf16(tf, af, sacc, 0, 0, 0);
        }
        int J = wv * 16 + i16;
        float vJ = sv[J], uJ = su[J];
#pragma unroll
        for (int r = 0; r < 4; ++r) {
            int I = wv * 16 + q * 4 + r;
            float val = (sacc[r] + su[I] * vJ + sv[I] * uJ + 16384.f * sv[I] * vJ) * 0.25f;
            float mx = val;
#pragma unroll
            for (int msk = 1; msk < 16; msk <<= 1) mx = fmaxf(mx, __shfl_xor(mx, msk));
            float e = __expf(val - mx);
            float sum = e;
#pragma unroll
            for (int msk = 1; msk < 16; msk <<= 1) sum += __shfl_xor(sum, msk);
            sW[I * 16 + i16] = e / sum;
        }
    }
    __syncthreads();

    // P = w_out * blkdiag(W)  (VALU -> bf16 into Ts) ; bias2 = P@sv + b_out
    {
        int c = t & 127, grp = t >> 7;
        unsigned short* Ps = Ts;
        float pb = 0.f;
#pragma unroll
        for (int hh = 0; hh < 2; ++hh) {
            int h = grp * 2 + hh;
            float wrow[16];
#pragma unroll
            for (int i = 0; i < 16; ++i) wrow[i] = w_out[c * 128 + h * 16 + i];
#pragma unroll
            for (int j = 0; j < 16; ++j) {
                float val = 0.f;
#pragma unroll
                for (int i = 0; i < 16; ++i) val += wrow[i] * sW[(h * 16 + i) * 16 + j];
                Ps[c * 136 + h * 16 + j] = f2bf(val);
                pb += val * sv[h * 16 + j];
            }
        }
        red[grp * 128 + c] = pb;
    }
    __syncthreads();
    if (t < 128)
        bias2[b * 128 + t] = b_out[t] + red[t] + red[128 + t] + red[256 + t] + red[384 + t];

    // M = P @ A  (MFMA: a = P rows, b = A^T rows)
    {
        f32x4 macc2[8];
#pragma unroll
        for (int ct = 0; ct < 8; ++ct) macc2[ct] = (f32x4){0.f, 0.f, 0.f, 0.f};
#pragma unroll
        for (int ks = 0; ks < 4; ++ks) {
            short8 pf = *(const short8*)&Ts[rA * 136 + ks * 32 + q * 8];
#pragma unroll
            for (int ct = 0; ct < 8; ++ct) {
                short8 atf = *(const short8*)&At[(ct * 16 + i16) * 136 + ks * 32 + q * 8];
                macc2[ct] = __builtin_amdgcn_mfma_f32_16x16x32_bf16(pf, atf, macc2[ct], 0, 0, 0);
            }
        }
        unsigned short* mb = Mb + (size_t)b * 16384;
#pragma unroll
        for (int ct = 0; ct < 8; ++ct)
#pragma unroll
            for (int r = 0; r < 4; ++r)
                mb[(wv * 16 + q * 4 + r) * 128 + ct * 16 + i16] = f2bf(macc2[ct][r]);
    }
}

// ---------------- K2: out = x + M @ x + bias2 (unchanged) ----------------
__global__ __launch_bounds__(256, 4) void k_out(const float* __restrict__ x,
                                                const unsigned short* __restrict__ Mb,
                                                const float* __restrict__ bias2,
                                                float* __restrict__ out) {
    __shared__ unsigned short Xt[128 * 128];   // [p][k] bf16, granule-swizzled
    __shared__ float b2s[128];

    const int t = threadIdx.x;
    const int lane = t & 63, wv = t >> 6;
    const int q = lane >> 4, i16 = lane & 15;
    const int b = blockIdx.x >> 7;
    const int p0 = (blockIdx.x & 127) << 7;

    if (t < 128) b2s[t] = bias2[b * 128 + t];

    const float* xb = x + (size_t)b * (128 * NPOS) + p0;
#pragma unroll
    for (int i = 0; i < 16; ++i) {
        int p = ((i & 1) << 6) + lane;
        int kq = (wv << 3) + (i >> 1);
        const float* col = xb + (size_t)(kq * 4) * NPOS + p;
        float a0 = col[0];
        float a1 = col[NPOS];
        float a2 = col[2 * NPOS];
        float a3 = col[3 * NPOS];
        ushort4 o; o.x = f2bf(a0); o.y = f2bf(a1); o.z = f2bf(a2); o.w = f2bf(a3);
        int g = kq >> 1;
        int sg = g ^ (p & 7);
        *(ushort4*)&Xt[p * 128 + (sg << 3) + ((kq & 1) << 2)] = o;
    }
    __syncthreads();

    f32x4 acc[2][8];
#pragma unroll
    for (int a = 0; a < 2; ++a)
#pragma unroll
        for (int pt = 0; pt < 8; ++pt) acc[a][pt] = (f32x4){0.f, 0.f, 0.f, 0.f};

    const unsigned short* Mrow = Mb + (size_t)b * 16384;
#pragma unroll
    for (int ks = 0; ks < 4; ++ks) {
        short8 a0 = *(const short8*)&Mrow[(wv * 32 + i16) * 128 + ks * 32 + q * 8];
        short8 a1 = *(const short8*)&Mrow[(wv * 32 + 16 + i16) * 128 + ks * 32 + q * 8];
        int g = ks * 4 + q;
#pragma unroll
        for (int pt = 0; pt < 8; ++pt) {
            int pr = pt * 16 + i16;
            short8 bb = *(const short8*)&Xt[pr * 128 + ((g ^ (pr & 7)) << 3)];
            acc[0][pt] = __builtin_amdgcn_mfma_f32_16x16x32_bf16(a0, bb, acc[0][pt], 0, 0, 0);
            acc[1][pt] = __builtin_amdgcn_mfma_f32_16x16x32_bf16(a1, bb, acc[1][pt], 0, 0, 0);
        }
    }

    float* ob = out + (size_t)b * (128 * NPOS) + p0;
#pragma unroll
    for (int a = 0; a < 2; ++a) {
        int cb = wv * 32 + a * 16 + q * 4;
#pragma unroll
        for (int pt = 0; pt < 8; ++pt) {
            int p = pt * 16 + i16;
#pragma unroll
            for (int r = 0; r < 4; ++r) {
                int c = cb + r;
                ob[(size_t)c * NPOS + p] = acc[a][pt][r] + b2s[c] + xb[(size_t)c * NPOS + p];
            }
        }
    }
}

extern "C" void kernel_launch(void* const* d_in, const int* in_sizes, int n_in,
                              void* d_out, int out_size, void* d_ws, size_t ws_size,
                              hipStream_t stream) {
    const float* x    = (const float*)d_in[0];
    const float* gn_w = (const float*)d_in[1];
    const float* gn_b = (const float*)d_in[2];
    const float* w_in = (const float*)d_in[3];
    const float* b_in = (const float*)d_in[4];
    const float* w_out= (const float*)d_in[5];
    const float* b_out= (const float*)d_in[6];
    float* out = (float*)d_out;

    // workspace (bytes), total ~8.7 MB:
    char* ws = (char*)d_ws;
    float* Gpart            = (float*)(ws + 0);         // 128*16384*4 = 8388608
    float* mpart            = (float*)(ws + 8388608);   // 128*128*4   = 65536
    unsigned long long* flagS = (unsigned long long*)(ws + 8454144);  // 1024
    unsigned long long* claim = (unsigned long long*)(ws + 8455168);  // 64
    float* bias2            = (float*)(ws + 8455232);   // 4096
    unsigned short* Mb      = (unsigned short*)(ws + 8459328); // 262144

    k_gramfold<<<dim3(128), dim3(512), 0, stream>>>(x, gn_w, gn_b, w_in, b_in,
                                                    w_out, b_out, Gpart, mpart,
                                                    flagS, claim, Mb, bias2);
    k_out<<<dim3(1024), dim3(256), 0, stream>>>(x, Mb, bias2, out);
}

// Round 8
// 200.367 us; speedup vs baseline: 1.5346x; 1.0668x over previous
//
#include <hip/hip_runtime.h>

// AttentionBlock: B=8, C=128, H=W=128, GROUPS=8, HEADS=8, HEAD_DIM=16
// R9: 3 dispatches. k_gram (R5-proven, 256 blocks) -> k_redfold -> k_out (R5-proven).
// k_redfold: 256 blocks = 8 b x 32 slices; each block wide-reduces a 4-row slice
// of G over 32 partials -> Gbf bf16 (+f32 diag, +m slice); last-arrival claim
// (R7-proven protocol); per-batch winner folds with only 32KB L2-hot bf16 input.
// Lesson from R7: wide phases on full grid; serial tails with tiny footprints.

#define NPOS 16384
#define MAG64   0x9E3779B97F4A7C15ull
#define CLAIM64 0xC1A1317E9E3779B9ull

typedef short short8 __attribute__((ext_vector_type(8)));   // 8 bf16
typedef float f32x4 __attribute__((ext_vector_type(4)));

__device__ __forceinline__ unsigned short f2bf(float f) {
    union { float f; unsigned u; } v; v.f = f;
    unsigned r = (v.u + 0x7fffu + ((v.u >> 16) & 1u)) >> 16;
    return (unsigned short)r;
}

// ---------------- K1: Gram partials (R5-proven) ----------------
// grid 256 = 8 b x 32 slabs of 512 pos; 2 chunks of 256 pos; 512 threads.
__global__ __launch_bounds__(512, 2) void k_gram(const float* __restrict__ x,
                                                 float* __restrict__ Gpart,
                                                 float* __restrict__ mpart) {
    __shared__ __align__(16) unsigned char SH[69632];

    const int t = threadIdx.x;
    const int lane = t & 63, wv = t >> 6;
    const int q = lane >> 4, i16 = lane & 15;
    const int blk = blockIdx.x;
    const int b = blk >> 5, slab = blk & 31;
    const size_t d0 = (size_t)slab << 9;      // 512 pos per block

    f32x4 acc[8];
    f32x4 macc = (f32x4){0.f, 0.f, 0.f, 0.f};
#pragma unroll
    for (int ct = 0; ct < 8; ++ct) acc[ct] = (f32x4){0.f, 0.f, 0.f, 0.f};
    const short8 ones = {(short)0x3F80, (short)0x3F80, (short)0x3F80, (short)0x3F80,
                         (short)0x3F80, (short)0x3F80, (short)0x3F80, (short)0x3F80};
    const float* xb = x + (size_t)b * (128 * NPOS) + d0;
    unsigned short* Xs = (unsigned short*)SH;   // [c=128][d=256] bf16, swizzled
    const int r0 = wv * 16 + i16;

    for (int cc = 0; cc < 2; ++cc) {
        if (cc) __syncthreads();
#pragma unroll
        for (int i = 0; i < 16; ++i) {
            int idx = t + i * 512;              // float4 index over [128][64]
            int c = idx >> 6, d4 = idx & 63;
            float4 v = *((const float4*)(xb + (size_t)c * NPOS + cc * 256) + d4);
            ushort4 o;
            o.x = f2bf(v.x); o.y = f2bf(v.y); o.z = f2bf(v.z); o.w = f2bf(v.w);
            int g = d4 >> 1;
            int sg = g ^ (c & 7);
            *(ushort4*)&Xs[c * 256 + (sg << 3) + ((d4 & 1) << 2)] = o;
        }
        __syncthreads();
#pragma unroll
        for (int ks = 0; ks < 8; ++ks) {
            int gd = ks * 4 + q;
            short8 af = *(const short8*)&Xs[r0 * 256 + ((gd ^ (r0 & 7)) << 3)];
            macc = __builtin_amdgcn_mfma_f32_16x16x32_bf16(af, ones, macc, 0, 0, 0);
#pragma unroll
            for (int ct = 0; ct < 8; ++ct) {
                int rb = ct * 16 + i16;
                short8 bb = *(const short8*)&Xs[rb * 256 + ((gd ^ (rb & 7)) << 3)];
                acc[ct] = __builtin_amdgcn_mfma_f32_16x16x32_bf16(af, bb, acc[ct], 0, 0, 0);
            }
        }
    }
    if (i16 == 0) {
#pragma unroll
        for (int r = 0; r < 4; ++r)
            mpart[blk * 128 + wv * 16 + q * 4 + r] = macc[r];
    }
    __syncthreads();            // Xs dead -> reuse as f32 [128][132]

    float* Tf = (float*)SH;
#pragma unroll
    for (int ct = 0; ct < 8; ++ct)
#pragma unroll
        for (int r = 0; r < 4; ++r)
            Tf[(wv * 16 + q * 4 + r) * 132 + ct * 16 + i16] = acc[ct][r];
    __syncthreads();
    float4* gp = (float4*)(Gpart + (size_t)blk * 16384);
#pragma unroll
    for (int i = 0; i < 8; ++i) {
        int fi = t + i * 512;
        int row = fi >> 5, c4 = fi & 31;
        gp[row * 32 + c4] = *(float4*)&Tf[row * 132 + c4 * 4];
    }
}

// ---------------- K2: wide reduce -> last-arrival -> fold ----------------
// grid 256 = 8 b x 32 slices (4 G-rows each); 512 threads; LDS ~117 KB.
__global__ __launch_bounds__(512, 1) void k_redfold(
    const float* __restrict__ Gpart, const float* __restrict__ mpart,
    const float* __restrict__ gn_w, const float* __restrict__ gn_b,
    const float* __restrict__ w_in, const float* __restrict__ b_in,
    const float* __restrict__ w_out, const float* __restrict__ b_out,
    unsigned long long* flagR, unsigned long long* claim,
    unsigned short* Gbf, float* Gdiag, float* mvG,
    unsigned short* __restrict__ Mb, float* __restrict__ bias2) {

    __shared__ __align__(16) unsigned char SH[119808];
    // reduce: redbuf f4[4][128] @0 (8KB); redm f32[4][4] @8192
    // fold:   As @0, At @34816, Ts @69632 (34816 each)
    //         sW @104448 (8KB); sm @112640; ss @113152; st @113664
    //         sv @114176; su @114688; red[8][128] @115712
    __shared__ int winner_s;

    const int t = threadIdx.x;
    const int lane = t & 63, wv = t >> 6;
    const int q = lane >> 4, i16 = lane & 15;
    const int blk = blockIdx.x;
    const int b = blk >> 5, p = blk & 31;

    // ======== wide reduce: slice rows [4p,4p+4) over 32 partials ========
    {
        float4* redbuf = (float4*)SH;
        float* redm = (float*)(SH + 8192);
        int f4i = t & 127, qtr = t >> 7;
        const float4* Gp4 = (const float4*)Gpart;
        size_t base = ((size_t)(b * 32 + qtr * 8)) * 4096 + p * 128 + f4i;
        float4 s = (float4){0.f, 0.f, 0.f, 0.f};
#pragma unroll
        for (int sl = 0; sl < 8; ++sl) {
            float4 v = Gp4[base + (size_t)sl * 4096];
            s.x += v.x; s.y += v.y; s.z += v.z; s.w += v.w;
        }
        redbuf[qtr * 128 + f4i] = s;
        if (f4i < 4) {
            int c = p * 4 + f4i;
            float ms = 0.f;
#pragma unroll
            for (int sl = 0; sl < 8; ++sl)
                ms += mpart[(b * 32 + qtr * 8 + sl) * 128 + c];
            redm[qtr * 4 + f4i] = ms;
        }
        __syncthreads();
        if (t < 128) {
            float4 a = redbuf[t], b4 = redbuf[128 + t];
            float4 c4v = redbuf[256 + t], d = redbuf[384 + t];
            float4 s2;
            s2.x = a.x + b4.x + c4v.x + d.x;
            s2.y = a.y + b4.y + c4v.y + d.y;
            s2.z = a.z + b4.z + c4v.z + d.z;
            s2.w = a.w + b4.w + c4v.w + d.w;
            int row = p * 4 + (t >> 5), col4 = t & 31;
            ushort4 o;
            o.x = f2bf(s2.x); o.y = f2bf(s2.y); o.z = f2bf(s2.z); o.w = f2bf(s2.w);
            *(ushort4*)&Gbf[b * 16384 + row * 128 + col4 * 4] = o;
            if (col4 == (row >> 2)) Gdiag[b * 128 + row] = ((float*)&s2)[row & 3];
        }
        if (t < 4)
            mvG[b * 128 + p * 4 + t] = redm[t] + redm[4 + t] + redm[8 + t] + redm[12 + t];
    }
    __threadfence();
    __syncthreads();

    // ======== publish flag, single check, claim (R7-proven) ========
    if (wv == 0) {
        if (lane == 0) atomicExch(&flagR[blk], MAG64 ^ (unsigned long long)blk);
        int pred = 1;
        if (lane < 32) {
            unsigned long long v = atomicAdd(&flagR[b * 32 + lane], 0ull);
            pred = (v == (MAG64 ^ (unsigned long long)(b * 32 + lane)));
        }
        int allok = __all(pred);
        if (lane == 0) {
            int win = 0;
            if (allok) {
                unsigned long long old = atomicExch(&claim[b], CLAIM64);
                win = (old != CLAIM64);
            }
            winner_s = win;
        }
    }
    __syncthreads();
    if (!winner_s) return;
    __threadfence();

    // ================= Tail (1 winner/batch): fold, 32KB bf16 input ==========
    unsigned short* As = (unsigned short*)SH;
    unsigned short* At = (unsigned short*)(SH + 34816);
    unsigned short* Ts = (unsigned short*)(SH + 69632);
    float* sW = (float*)(SH + 104448);
    float* sm = (float*)(SH + 112640);
    float* ss = (float*)(SH + 113152);
    float* st = (float*)(SH + 113664);
    float* sv = (float*)(SH + 114176);
    float* su = (float*)(SH + 114688);
    float* red = (float*)(SH + 115712);         // [8][128]

    if (t < 128) sm[t] = mvG[b * 128 + t];
    __syncthreads();

    // stats (Gdiag f32 from global, L2-hot)
    if (t < 128) {
        int g = t >> 4;
        float s1 = 0.f, s2 = 0.f;
#pragma unroll
        for (int k = 0; k < 16; ++k) {
            int c = g * 16 + k;
            s1 += sm[c];
            s2 += Gdiag[b * 128 + c];
        }
        const float invN = 1.0f / 262144.0f;
        float mean = s1 * invN;
        float var = s2 * invN - mean * mean;
        float rstd = rsqrtf(var + 1e-5f);
        float s = gn_w[t] * rstd;
        ss[t] = s;
        st[t] = gn_b[t] - mean * s;
    }
    __syncthreads();

    // A (+A^T) bf16 ; v,u partials
    {
        int c = t & 127, quarter = t >> 7;
        float v = 0.f, u = 0.f;
        const float* wr = w_in + c * 128 + quarter * 32;
        unsigned short* ar = &As[c * 136 + quarter * 32];
#pragma unroll
        for (int k = 0; k < 32; ++k) {
            int kg = quarter * 32 + k;
            float w = wr[k];
            float a = w * ss[kg];
            unsigned short ab = f2bf(a);
            ar[k] = ab;
            At[kg * 136 + c] = ab;
            v += w * st[kg];
            u += a * sm[kg];
        }
        red[quarter * 128 + c] = v;
        red[(4 + quarter) * 128 + c] = u;
    }
    // stage Gbf (bf16, 32KB, L2-hot) -> Ts
    {
        const ushort4* gb4 = (const ushort4*)(Gbf + b * 16384);
        for (int i4 = t; i4 < 4096; i4 += 512) {
            int row = i4 >> 5, c4 = i4 & 31;
            *(ushort4*)&Ts[row * 136 + c4 * 4] = gb4[i4];
        }
    }
    __syncthreads();
    if (t < 128) {
        sv[t] = b_in[t] + red[t] + red[128 + t] + red[256 + t] + red[384 + t];
        su[t] = red[512 + t] + red[640 + t] + red[768 + t] + red[896 + t];
    }
    __syncthreads();

    // T = A @ G  (G symmetric)
    f32x4 tacc[8];
#pragma unroll
    for (int ct = 0; ct < 8; ++ct) tacc[ct] = (f32x4){0.f, 0.f, 0.f, 0.f};
    const int rA = wv * 16 + i16;
#pragma unroll
    for (int ks = 0; ks < 4; ++ks) {
        short8 af = *(const short8*)&As[rA * 136 + ks * 32 + q * 8];
#pragma unroll
        for (int ct = 0; ct < 8; ++ct) {
            short8 gbf2 = *(const short8*)&Ts[(ct * 16 + i16) * 136 + ks * 32 + q * 8];
            tacc[ct] = __builtin_amdgcn_mfma_f32_16x16x32_bf16(af, gbf2, tacc[ct], 0, 0, 0);
        }
    }
    __syncthreads();
#pragma unroll
    for (int ct = 0; ct < 8; ++ct)
#pragma unroll
        for (int r = 0; r < 4; ++r)
            Ts[(wv * 16 + q * 4 + r) * 136 + ct * 16 + i16] = f2bf(tacc[ct][r]);
    __syncthreads();

    // S_h = T_h A_h^T + rank-1 ; softmax -> sW (wave = head)
    {
        f32x4 sacc = (f32x4){0.f, 0.f, 0.f, 0.f};
#pragma unroll
        for (int ks = 0; ks < 4; ++ks) {
            short8 tf = *(const short8*)&Ts[rA * 136 + ks * 32 + q * 8];
            short8 af = *(const short8*)&As[rA * 136 + ks * 32 + q * 8];
            sacc = __builtin_amdgcn_mfma_f32_16x16x32_bf16(tf, af, sacc, 0, 0, 0);
        }
        int J = wv * 16 + i16;
        float vJ = sv[J], uJ = su[J];
#pragma unroll
        for (int r = 0; r < 4; ++r) {
            int I = wv * 16 + q * 4 + r;
            float val = (sacc[r] + su[I] * vJ + sv[I] * uJ + 16384.f * sv[I] * vJ) * 0.25f;
            float mx = val;
#pragma unroll
            for (int msk = 1; msk < 16; msk <<= 1) mx = fmaxf(mx, __shfl_xor(mx, msk));
            float e = __expf(val - mx);
            float sum = e;
#pragma unroll
            for (int msk = 1; msk < 16; msk <<= 1) sum += __shfl_xor(sum, msk);
            sW[I * 16 + i16] = e / sum;
        }
    }
    __syncthreads();

    // P = w_out * blkdiag(W)  (VALU -> bf16 into Ts) ; bias2 = P@sv + b_out
    {
        int c = t & 127, grp = t >> 7;
        unsigned short* Ps = Ts;
        float pb = 0.f;
#pragma unroll
        for (int hh = 0; hh < 2; ++hh) {
            int h = grp * 2 + hh;
            float wrow[16];
#pragma unroll
            for (int i = 0; i < 16; ++i) wrow[i] = w_out[c * 128 + h * 16 + i];
#pragma unroll
            for (int j = 0; j < 16; ++j) {
                float val = 0.f;
#pragma unroll
                for (int i = 0; i < 16; ++i) val += wrow[i] * sW[(h * 16 + i) * 16 + j];
                Ps[c * 136 + h * 16 + j] = f2bf(val);
                pb += val * sv[h * 16 + j];
            }
        }
        red[grp * 128 + c] = pb;
    }
    __syncthreads();
    if (t < 128)
        bias2[b * 128 + t] = b_out[t] + red[t] + red[128 + t] + red[256 + t] + red[384 + t];

    // M = P @ A  (MFMA: a = P rows, b = A^T rows)
    {
        f32x4 macc2[8];
#pragma unroll
        for (int ct = 0; ct < 8; ++ct) macc2[ct] = (f32x4){0.f, 0.f, 0.f, 0.f};
#pragma unroll
        for (int ks = 0; ks < 4; ++ks) {
            short8 pf = *(const short8*)&Ts[rA * 136 + ks * 32 + q * 8];
#pragma unroll
            for (int ct = 0; ct < 8; ++ct) {
                short8 atf = *(const short8*)&At[(ct * 16 + i16) * 136 + ks * 32 + q * 8];
                macc2[ct] = __builtin_amdgcn_mfma_f32_16x16x32_bf16(pf, atf, macc2[ct], 0, 0, 0);
            }
        }
        unsigned short* mb = Mb + (size_t)b * 16384;
#pragma unroll
        for (int ct = 0; ct < 8; ++ct)
#pragma unroll
            for (int r = 0; r < 4; ++r)
                mb[(wv * 16 + q * 4 + r) * 128 + ct * 16 + i16] = f2bf(macc2[ct][r]);
    }
}

// ---------------- K3: out = x + M @ x + bias2 (unchanged) ----------------
__global__ __launch_bounds__(256, 4) void k_out(const float* __restrict__ x,
                                                const unsigned short* __restrict__ Mb,
                                                const float* __restrict__ bias2,
                                                float* __restrict__ out) {
    __shared__ unsigned short Xt[128 * 128];   // [p][k] bf16, granule-swizzled
    __shared__ float b2s[128];

    const int t = threadIdx.x;
    const int lane = t & 63, wv = t >> 6;
    const int q = lane >> 4, i16 = lane & 15;
    const int b = blockIdx.x >> 7;
    const int p0 = (blockIdx.x & 127) << 7;

    if (t < 128) b2s[t] = bias2[b * 128 + t];

    const float* xb = x + (size_t)b * (128 * NPOS) + p0;
#pragma unroll
    for (int i = 0; i < 16; ++i) {
        int p = ((i & 1) << 6) + lane;
        int kq = (wv << 3) + (i >> 1);
        const float* col = xb + (size_t)(kq * 4) * NPOS + p;
        float a0 = col[0];
        float a1 = col[NPOS];
        float a2 = col[2 * NPOS];
        float a3 = col[3 * NPOS];
        ushort4 o; o.x = f2bf(a0); o.y = f2bf(a1); o.z = f2bf(a2); o.w = f2bf(a3);
        int g = kq >> 1;
        int sg = g ^ (p & 7);
        *(ushort4*)&Xt[p * 128 + (sg << 3) + ((kq & 1) << 2)] = o;
    }
    __syncthreads();

    f32x4 acc[2][8];
#pragma unroll
    for (int a = 0; a < 2; ++a)
#pragma unroll
        for (int pt = 0; pt < 8; ++pt) acc[a][pt] = (f32x4){0.f, 0.f, 0.f, 0.f};

    const unsigned short* Mrow = Mb + (size_t)b * 16384;
#pragma unroll
    for (int ks = 0; ks < 4; ++ks) {
        short8 a0 = *(const short8*)&Mrow[(wv * 32 + i16) * 128 + ks * 32 + q * 8];
        short8 a1 = *(const short8*)&Mrow[(wv * 32 + 16 + i16) * 128 + ks * 32 + q * 8];
        int g = ks * 4 + q;
#pragma unroll
        for (int pt = 0; pt < 8; ++pt) {
            int pr = pt * 16 + i16;
            short8 bb = *(const short8*)&Xt[pr * 128 + ((g ^ (pr & 7)) << 3)];
            acc[0][pt] = __builtin_amdgcn_mfma_f32_16x16x32_bf16(a0, bb, acc[0][pt], 0, 0, 0);
            acc[1][pt] = __builtin_amdgcn_mfma_f32_16x16x32_bf16(a1, bb, acc[1][pt], 0, 0, 0);
        }
    }

    float* ob = out + (size_t)b * (128 * NPOS) + p0;
#pragma unroll
    for (int a = 0; a < 2; ++a) {
        int cb = wv * 32 + a * 16 + q * 4;
#pragma unroll
        for (int pt = 0; pt < 8; ++pt) {
            int p = pt * 16 + i16;
#pragma unroll
            for (int r = 0; r < 4; ++r) {
                int c = cb + r;
                ob[(size_t)c * NPOS + p] = acc[a][pt][r] + b2s[c] + xb[(size_t)c * NPOS + p];
            }
        }
    }
}

extern "C" void kernel_launch(void* const* d_in, const int* in_sizes, int n_in,
                              void* d_out, int out_size, void* d_ws, size_t ws_size,
                              hipStream_t stream) {
    const float* x    = (const float*)d_in[0];
    const float* gn_w = (const float*)d_in[1];
    const float* gn_b = (const float*)d_in[2];
    const float* w_in = (const float*)d_in[3];
    const float* b_in = (const float*)d_in[4];
    const float* w_out= (const float*)d_in[5];
    const float* b_out= (const float*)d_in[6];
    float* out = (float*)d_out;

    // workspace (bytes), total ~17.5 MB:
    char* ws = (char*)d_ws;
    float* Gpart            = (float*)(ws + 0);          // 256*16384*4 = 16777216
    float* mpart            = (float*)(ws + 16777216);   // 256*128*4   = 131072
    unsigned long long* flagR = (unsigned long long*)(ws + 16908288); // 2048
    unsigned long long* claim = (unsigned long long*)(ws + 16910336); // 64
    unsigned short* Gbf     = (unsigned short*)(ws + 16910400); // 262144
    float* Gdiag            = (float*)(ws + 17172544);   // 4096
    float* mvG              = (float*)(ws + 17176640);   // 4096
    float* bias2            = (float*)(ws + 17180736);   // 4096
    unsigned short* Mb      = (unsigned short*)(ws + 17184832); // 262144

    k_gram<<<dim3(256), dim3(512), 0, stream>>>(x, Gpart, mpart);
    k_redfold<<<dim3(256), dim3(512), 0, stream>>>(Gpart, mpart, gn_w, gn_b,
                                                   w_in, b_in, w_out, b_out,
                                                   flagR, claim, Gbf, Gdiag, mvG,
                                                   Mb, bias2);
    k_out<<<dim3(1024), dim3(256), 0, stream>>>(x, Mb, bias2, out);
}